// Round 6
// baseline (123.281 us; speedup 1.0000x reference)
//
#include <hip/hip_runtime.h>

#define N 4096
#define D 512
#define C 64
#define MARGIN 1.0f
#define WT 64                        // wave-tile: one wave owns a 64x64 output tile
#define NWT (N / WT)                 // 64 tiles per side
#define NTRI_W (NWT * (NWT + 1) / 2) // 2080 triangular wave-tiles (2080 % 8 == 0)
#define FINF 3.0e38f
#define SLOTW 16
#define PCAP 256       // per-tile pair capacity (mean ~64 off-diag, ~32 diag; +24 sigma)
#define LOSSB 128      // loss_kernel blocks

typedef __attribute__((ext_vector_type(8))) short short8;
typedef __attribute__((ext_vector_type(4))) float floatx4;

__device__ __forceinline__ unsigned short f2bf(float f) {
  unsigned int u = __float_as_uint(f);
  u += 0x7FFFu + ((u >> 16) & 1u);  // RNE
  return (unsigned short)(u >> 16);
}

// K1: fp32 -> bf16 in FRAGMENT-NATIVE TILED layout + exact fp32 squared norms.
// Tiled layout (R4-verified): dword index = tile16*4096 + kchunk32*256 +
// row16*16 + kpair, i.e. [tile(16 rows)][kchunk(32 k)][row][16 dwords].
// A wave's MFMA fragment (16 rows x 32 k) is 1 KB CONTIGUOUS: lane(l16,quad)
// reads byte l16*64 + quad*16 -> one fully-coalesced global_load_dwordx4.
// Blocks 0..N-1: one row each. Blocks 0..15 also init an_sq to +inf.
// Block N: zero accs/done/pair_cursor.
__global__ __launch_bounds__(256) void prep_kernel(const float* __restrict__ E,
                                                   unsigned int* __restrict__ Ebt,
                                                   float* __restrict__ norms,
                                                   unsigned int* __restrict__ an_sq_bits,
                                                   unsigned int* __restrict__ accs_u,
                                                   unsigned int* __restrict__ ctrl) {
  const int row = blockIdx.x;
  const int tid = threadIdx.x;
  if (row == N) {  // control-init block
    for (int k = tid; k < C * SLOTW; k += 256) accs_u[k] = 0u;
    if (tid < 2) ctrl[tid] = 0u;  // ctrl[0]=pair_cursor, ctrl[1]=done
    return;
  }
  if (row < 16) an_sq_bits[row * 256 + tid] = 0x7F800000u;  // +inf
  const float2 v = reinterpret_cast<const float2*>(E + (size_t)row * D)[tid];
  float s = v.x * v.x + v.y * v.y;
  unsigned int packed = ((unsigned int)f2bf(v.y) << 16) | (unsigned int)f2bf(v.x);
  // k = 2*tid: tile=row>>4, kchunk=tid>>4, r=row&15, kpair=tid&15
  Ebt[((size_t)(row >> 4) << 12) + ((tid >> 4) << 8) + ((row & 15) << 4) + (tid & 15)] = packed;
  for (int off = 32; off > 0; off >>= 1) s += __shfl_down(s, off);
  __shared__ float wsum[4];
  if ((tid & 63) == 0) wsum[tid >> 6] = s;
  __syncthreads();
  if (tid == 0) norms[row] = wsum[0] + wsum[1] + wsum[2] + wsum[3];
}

// K2: E*E^T via bf16 MFMA. ONE WAVE PER 64x64 TILE (2080 one-wave blocks),
// register-direct coalesced fragment loads from the tiled layout, ZERO K-loop
// barriers / ZERO K-loop LDS. Rationale (R0-R5 counters): every LDS-staged
// variant ran at 3-6 TB/s effective (barrier-throttled, MfmaUtil 5-7%); the
// barrier-free reg-direct R4 ran at ~9.7 TB/s (fabric limit) but carried 4x
// traffic. This version keeps R4's load path, halves R4's traffic via 64x64
// acc[4][4] per wave (266 MB total), and adds CELL-BLOCKED XCD mapping:
// the tile triangle is split into ten 16x16-tile cells (6 off-diag @ 2 MB
// footprint, 4 diag @ 1 MB); each XCD's 260 resident blocks cover ~1 cell,
// so its instantaneous working set (<=3 MB) fits the 4 MB L2 with headroom
// (the old column-swizzle hit ~4 MB = thrash to L3).
// Fused epilogue: (a) masked min over negatives -> atomicMin(an_sq_bits);
// (b) emit same-class pairs (i<j) as records {i<<12|j, sq}, LDS-compacted,
// one global cursor-add per block.
__global__ __launch_bounds__(64, 2) void gemm_min_kernel(const unsigned int* __restrict__ Ebt,
                                                         const float* __restrict__ norms,
                                                         const int* __restrict__ targets,
                                                         unsigned int* __restrict__ an_sq_bits,
                                                         uint2* __restrict__ pairs,
                                                         unsigned int* __restrict__ ctrl) {
  // XCD-contiguous ordered index (dispatch: blockIdx % 8 -> XCD; 2080/8 = 260)
  const int o = (blockIdx.x & 7) * (NTRI_W / 8) + (blockIdx.x >> 3);
  int tm, tn;  // 64-row tile coords, tm <= tn
  if (o < 1536) {  // 6 off-diagonal cells of 16x16 tiles, 256 tiles each
    const int w = o >> 8, t = o & 255;
    const int r = (w < 3) ? 0 : ((w < 5) ? 1 : 2);
    const int c = (w < 3) ? (w + 1) : ((w < 5) ? (w - 1) : 3);
    tm = r * 16 + (t >> 4);
    tn = c * 16 + (t & 15);
  } else {  // 4 diagonal cells, 136 tiles each (i<=j triangle of 16)
    const int q = o - 1536;
    const int d = q / 136, t = q - d * 136;
    int j = (int)((sqrtf(8.0f * (float)t + 1.0f) - 1.0f) * 0.5f);
    while ((j + 1) * (j + 2) / 2 <= t) ++j;
    while (j * (j + 1) / 2 > t) --j;
    tm = d * 16 + (t - j * (j + 1) / 2);
    tn = d * 16 + j;
  }

  __shared__ unsigned int s_pkey[PCAP];  // 1 KB
  __shared__ float s_psq[PCAP];          // 1 KB
  __shared__ unsigned int s_pcnt, s_pbase;

  const int lane = threadIdx.x;  // one wave
  const int quad = lane >> 4, l16 = lane & 15;
  const int rowBase = tm * WT, colBase = tn * WT;
  if (lane == 0) s_pcnt = 0u;
  __syncthreads();

  // Fragment stream bases (R4-verified addressing): 16-row subtile s of this
  // 64-row tile is tile16 index tm*4+s; 1 KB contiguous per (tile16,kchunk);
  // lane offset l16*64 + quad*16; kchunk step 1024 B.
  const unsigned char* Eb = (const unsigned char*)Ebt;
  const int lbyte = l16 * 64 + quad * 16;
  const unsigned char* pA[4];
  const unsigned char* pB[4];
#pragma unroll
  for (int s = 0; s < 4; s++) {
    pA[s] = Eb + ((size_t)(tm * 4 + s) << 14) + lbyte;
    pB[s] = Eb + ((size_t)(tn * 4 + s) << 14) + lbyte;
  }

  floatx4 acc[4][4];
#pragma unroll
  for (int a = 0; a < 4; a++)
#pragma unroll
    for (int b = 0; b < 4; b++) acc[a][b] = (floatx4){0.f, 0.f, 0.f, 0.f};

  // 16 K-chunks of 32 k-elems; fully unrolled, no barriers, no LDS. The 8
  // loads per chunk are independent -> compiler pipelines with counted vmcnt.
#pragma unroll
  for (int c = 0; c < 16; ++c) {
    short8 af[4], bf[4];
#pragma unroll
    for (int s = 0; s < 4; s++) {
      af[s] = *reinterpret_cast<const short8*>(pA[s] + c * 1024);
      bf[s] = *reinterpret_cast<const short8*>(pB[s] + c * 1024);
    }
#pragma unroll
    for (int sm = 0; sm < 4; sm++)
#pragma unroll
      for (int sn = 0; sn < 4; sn++)
        acc[sm][sn] = __builtin_amdgcn_mfma_f32_16x16x32_bf16(af[sm], bf[sn], acc[sm][sn], 0, 0, 0);
  }

  // Epilogue. C/D layout: col = lane&15, row = quad*4 + reg (m89/m91).
  int tcol[4], gcolv[4];
  float ncol[4];
#pragma unroll
  for (int sn = 0; sn < 4; sn++) {
    const int gc = colBase + sn * 16 + l16;
    gcolv[sn] = gc;
    tcol[sn] = targets[gc];
    ncol[sn] = norms[gc];
  }
  float colmin[4] = {FINF, FINF, FINF, FINF};
#pragma unroll
  for (int sm = 0; sm < 4; sm++) {
#pragma unroll
    for (int r = 0; r < 4; r++) {
      const int grow = rowBase + sm * 16 + quad * 4 + r;
      const int trow = targets[grow];
      const float nrow = norms[grow];
      float rowmin = FINF;
#pragma unroll
      for (int sn = 0; sn < 4; sn++) {
        const float sq = fmaxf(nrow + ncol[sn] - 2.0f * acc[sm][sn][r], 0.0f);
        if (tcol[sn] != trow) {
          rowmin = fminf(rowmin, sq);
          colmin[sn] = fminf(colmin[sn], sq);
        } else if (grow < gcolv[sn]) {  // same-class anchor-positive pair (i<j): emit
          const unsigned int idx = atomicAdd(&s_pcnt, 1u);
          if (idx < PCAP) {
            s_pkey[idx] = ((unsigned int)grow << 12) | (unsigned int)gcolv[sn];
            s_psq[idx] = sq;
          } else {  // overflow fallback (astronomically rare): direct global emit
            const unsigned int g = atomicAdd(&ctrl[0], 1u);
            pairs[g] = make_uint2(((unsigned int)grow << 12) | (unsigned int)gcolv[sn],
                                  __float_as_uint(sq));
          }
        }
      }
      // row-min over this wave's 64 cols: 4 sn frags in-lane + 16 l16 lanes
#pragma unroll
      for (int off = 1; off < 16; off <<= 1) rowmin = fminf(rowmin, __shfl_xor(rowmin, off));
      if (l16 == 0 && rowmin < FINF) atomicMin(&an_sq_bits[grow], __float_as_uint(rowmin));
    }
  }
  // col-min over the wave's 64 rows: reduce across quads (lanes 16,32 apart)
#pragma unroll
  for (int sn = 0; sn < 4; sn++) {
    float cm = colmin[sn];
    cm = fminf(cm, __shfl_xor(cm, 16));
    cm = fminf(cm, __shfl_xor(cm, 32));
    if (quad == 0 && cm < FINF)
      atomicMin(&an_sq_bits[colBase + sn * 16 + l16], __float_as_uint(cm));
  }
  // flush the compacted pair list: ONE global cursor-add per block
  __syncthreads();
  const unsigned int npair = min(s_pcnt, (unsigned int)PCAP);
  if (lane == 0) s_pbase = atomicAdd(&ctrl[0], npair);
  __syncthreads();
  for (unsigned int r = lane; r < npair; r += 64)
    pairs[s_pbase + r] = make_uint2(s_pkey[r], __float_as_uint(s_psq[r]));
}

// K3: flat pass over emitted pair records. loss = relu(sq - an + margin) if the
// mined (euclidean) loss is strictly positive; anchor = smaller index (emit order).
__global__ __launch_bounds__(256) void loss_kernel(const uint2* __restrict__ pairs,
                                                   const unsigned int* __restrict__ an_sq_bits,
                                                   float* __restrict__ accs,
                                                   unsigned int* __restrict__ ctrl,
                                                   float* __restrict__ out) {
  const int tid = threadIdx.x, wave = tid >> 6, lane = tid & 63;
  const unsigned int M = ctrl[0];
  __shared__ float s_sum[4];
  __shared__ unsigned int s_cnt[4], s_cor[4];
  __shared__ int s_last;
  float bsum = 0.f;
  unsigned int bcnt = 0, bcor = 0;
  for (unsigned int r = blockIdx.x * 256 + tid; r < M; r += LOSSB * 256) {
    const uint2 rec = pairs[r];
    const int a = (int)(rec.x >> 12);  // anchor (smaller original index)
    const float sq = __uint_as_float(rec.y);
    const float an = __uint_as_float(an_sq_bits[a]);
    if (sqrtf(sq) - sqrtf(an) + MARGIN > 0.0f) {
      bcnt++;
      bsum += fmaxf(sq - an + MARGIN, 0.0f);
      if (sq < an) bcor++;
    }
  }
#pragma unroll
  for (int off = 32; off > 0; off >>= 1) {
    bsum += __shfl_down(bsum, off);
    bcnt += __shfl_down(bcnt, off);
    bcor += __shfl_down(bcor, off);
  }
  if (lane == 0) { s_sum[wave] = bsum; s_cnt[wave] = bcnt; s_cor[wave] = bcor; }
  __syncthreads();
  if (tid == 0) {
    float* slot = accs + (size_t)(blockIdx.x & (C - 1)) * SLOTW;
    atomicAdd(&slot[0], s_sum[0] + s_sum[1] + s_sum[2] + s_sum[3]);
    atomicAdd((unsigned int*)&slot[1], s_cnt[0] + s_cnt[1] + s_cnt[2] + s_cnt[3]);
    atomicAdd((unsigned int*)&slot[2], s_cor[0] + s_cor[1] + s_cor[2] + s_cor[3]);
    __threadfence();  // release
    s_last = (atomicAdd(&ctrl[1], 1u) == (unsigned int)LOSSB - 1u);
  }
  __syncthreads();
  if (s_last) {  // last block: reduce the 64 slots, finalize the two scalars
    __threadfence();  // acquire
    if (tid < C) {
      float sum = __uint_as_float(atomicAdd((unsigned int*)&accs[(size_t)tid * SLOTW + 0], 0u));
      unsigned int cnt = atomicAdd((unsigned int*)&accs[(size_t)tid * SLOTW + 1], 0u);
      unsigned int cor = atomicAdd((unsigned int*)&accs[(size_t)tid * SLOTW + 2], 0u);
#pragma unroll
      for (int off = 32; off > 0; off >>= 1) {
        sum += __shfl_down(sum, off);
        cnt += __shfl_down(cnt, off);
        cor += __shfl_down(cor, off);
      }
      if (tid == 0) {
        const float denom = (float)(cnt > 0u ? cnt : 1u);
        out[0] = sum / denom;
        out[1] = (float)cor / denom;
      }
    }
  }
}

extern "C" void kernel_launch(void* const* d_in, const int* in_sizes, int n_in,
                              void* d_out, int out_size, void* d_ws, size_t ws_size,
                              hipStream_t stream) {
  const float* E = (const float*)d_in[0];
  const int* targets = (const int*)d_in[1];
  float* out = (float*)d_out;
  char* ws = (char*)d_ws;
  size_t off = 0;
  unsigned int* Ebt = (unsigned int*)(ws + off); off += (size_t)N * D * 2;      // 4 MB (tiled bf16)
  float* norms = (float*)(ws + off); off += (size_t)N * 4;                      // 16 KB
  unsigned int* an_sq = (unsigned int*)(ws + off); off += (size_t)N * 4;        // 16 KB
  float* accs = (float*)(ws + off); off += (size_t)C * SLOTW * 4;               // 4 KB
  unsigned int* ctrl = (unsigned int*)(ws + off); off += 256;                   // cursor+done
  uint2* pairs = (uint2*)(ws + off);                                            // ~70 MB max

  prep_kernel<<<dim3(N + 1), dim3(256), 0, stream>>>(E, Ebt, norms, an_sq, (unsigned int*)accs, ctrl);
  gemm_min_kernel<<<dim3(NTRI_W), dim3(64), 0, stream>>>(Ebt, norms, targets, an_sq, pairs, ctrl);
  loss_kernel<<<dim3(LOSSB), dim3(256), 0, stream>>>(pairs, an_sq, accs, ctrl, out);
}